// Round 5
// baseline (415.385 us; speedup 1.0000x reference)
//
#include <hip/hip_runtime.h>

#define KH 5
#define KW 5
#define CIN 16
#define NF 32
#define H 224
#define W 224
#define HO 220
#define WO 220
#define RPB 4              // output rows per block
#define XROWS (RPB + KH - 1)   // 8 input rows staged
#define WPAD 32            // taps padded 25 -> 32 floats (128 B) for s_load_dwordx16
#define NTILE (HO / RPB)   // 55 ho-tiles
#define NBLK (CIN * NTILE * 4)  // 3520 blocks; 3520 % 8 == 0 -> bijective XCD swizzle
#define NXCD 8
#define CPX (NBLK / NXCD)  // 440 blocks per XCD chunk

typedef float v2f __attribute__((ext_vector_type(2)));

// ---- pre-kernel: transpose weights [tap][c][f] -> Wt[c][f][tap(pad 32)] ----
__global__ void transpose_weights(const float* __restrict__ Kw,
                                  float* __restrict__ Wt) {
    int idx = blockIdx.x * 256 + threadIdx.x;     // over KH*KW*CIN*NF = 12800
    if (idx < KH * KW * CIN * NF) {
        const int tap = idx / (CIN * NF);
        const int rem = idx - tap * (CIN * NF);
        const int c   = rem >> 5;                 // / NF
        const int f   = rem & 31;                 // % NF
        Wt[((size_t)(c * NF) + f) * WPAD + tap] = Kw[idx];
    }
}

// x-pair starting at column m of window row a: even m from xe, odd m from xo
#define XPAIR(a, m) (((m) & 1) ? xo[a][((m) - 1) / 2] : xe[a][(m) / 2])

// compute one filter's packed accumulators from the paired window and store.
// acc2[r][0] = outputs (q0,q1), acc2[r][1] = (q2,q3): 200 v_pk_fma_f32
// (vs 400 v_fmac_f32) per filter; weight splat broadcasts from SGPR.
__device__ __forceinline__ void compute_store(
    const v2f (&xe)[XROWS][4], const v2f (&xo)[XROWS][3],
    const float (&wk)[KH * KW],
    const uint32_t (&obase)[RPB], int f, float* __restrict__ O)
{
    v2f acc[RPB][2];
#pragma unroll
    for (int r = 0; r < RPB; ++r) {
        acc[r][0] = (v2f){0.0f, 0.0f};
        acc[r][1] = (v2f){0.0f, 0.0f};
    }

#pragma unroll
    for (int i = 0; i < KH; ++i)
#pragma unroll
        for (int j = 0; j < KW; ++j) {
            const float w = wk[i * KW + j];
            const v2f w2 = {w, w};
#pragma unroll
            for (int r = 0; r < RPB; ++r) {
                const int a = r + i;
                acc[r][0] = __builtin_elementwise_fma(XPAIR(a, j),     w2, acc[r][0]);
                acc[r][1] = __builtin_elementwise_fma(XPAIR(a, j + 2), w2, acc[r][1]);
            }
        }

#pragma unroll
    for (int r = 0; r < RPB; ++r)
        *(float4*)&O[obase[r] + (uint32_t)f * WO] =
            make_float4(acc[r][0].x, acc[r][0].y, acc[r][1].x, acc[r][1].y);
}

// ---- main kernel: one block per (c, ho-tile of 4, b); wave -> filter octet ----
// R4 structure (weight s_load ping-pong, XCD swizzle, unrolled staging) +
// packed fp32: v_pk_fma_f32 halves FMA issue cycles (fp32 peak on CDNA4
// requires VOP3P packed math). Window held as even pairs xe[8][4] + odd-offset
// duplicate pairs xo[8][3] so every tap's x-pair is register-aligned.
// Math exact in fp32 (x < 256, |k| <= 8, sums < 2^24).
__global__ __launch_bounds__(256) void conv2d_main(
    const float* __restrict__ X,    // [B, H, W, CIN]
    const float* __restrict__ Wt,   // [CIN, NF, WPAD]
    float* __restrict__ O)          // [B, HO, CIN, NF, WO]
{
    __shared__ float xs[XROWS * W];   // 7168 B

    // bijective XCD swizzle: hw blocks i, i+8, .. execute logical chunk i
    const int bid = blockIdx.x;
    const int l   = (bid & 7) * CPX + (bid >> 3);
    const int c   = l & 15;            // logical order: c fastest, then hoT, b
    const int rest = l >> 4;
    const int hoT = rest % NTILE;
    const int b   = rest / NTILE;
    const int ho0 = hoT * RPB;
    const int t   = threadIdx.x;

    // stage input rows ho0..ho0+7 of channel c (strided gather by CIN floats)
    const uint32_t xoff = ((uint32_t)(b * H + ho0) * W) * CIN + c;
#pragma unroll
    for (int k = 0; k < XROWS * W / 256; ++k) {
        const int idx = t + k * 256;
        xs[idx] = X[xoff + (uint32_t)idx * CIN];
    }
    __syncthreads();

    const int wave = t >> 6;
    const int lane = t & 63;
    const int wo0  = lane * 4;
    if (lane >= 55) return;          // 55*4 = 220 = WO; no barrier after this

    // paired x window: 8 rows x (4 even pairs + 3 odd-offset pairs)
    v2f xe[XROWS][4], xo[XROWS][3];
#pragma unroll
    for (int r = 0; r < XROWS; ++r) {
        const float4 xa = *(const float4*)&xs[r * W + wo0];
        const float4 xb = *(const float4*)&xs[r * W + wo0 + 4];
        xe[r][0] = (v2f){xa.x, xa.y}; xe[r][1] = (v2f){xa.z, xa.w};
        xe[r][2] = (v2f){xb.x, xb.y}; xe[r][3] = (v2f){xb.z, xb.w};
        xo[r][0] = (v2f){xa.y, xa.z}; xo[r][1] = (v2f){xa.w, xb.x};
        xo[r][2] = (v2f){xb.y, xb.z};
    }

    // per-output-row store bases (uint32: total output floats < 2^31)
    uint32_t obase[RPB];
#pragma unroll
    for (int r = 0; r < RPB; ++r)
        obase[r] = (((uint32_t)(b * HO + ho0 + r) * CIN + c) * NF) * WO + wo0;

    const float* wc = Wt + (size_t)(c * NF) * WPAD;
    const int f0 = __builtin_amdgcn_readfirstlane(wave * 8);

    // 2-deep ping-pong weight pipeline (uniform addresses -> SGPR s_loads)
    float wkA[KH * KW], wkB[KH * KW];
    {
        const float* wp = wc + (size_t)f0 * WPAD;
#pragma unroll
        for (int tap = 0; tap < KH * KW; ++tap) wkA[tap] = wp[tap];
    }

#pragma unroll 1
    for (int fi = 0; fi < 8; fi += 2) {
        // prefetch filter fi+1 into B before consuming A
        {
            const float* wp = wc + (size_t)(f0 + fi + 1) * WPAD;
#pragma unroll
            for (int tap = 0; tap < KH * KW; ++tap) wkB[tap] = wp[tap];
        }
        compute_store(xe, xo, wkA, obase, f0 + fi, O);

        // prefetch filter fi+2 into A ( &7 wraps last iter in-bounds, unused )
        {
            const float* wp = wc + (size_t)(f0 + ((fi + 2) & 7)) * WPAD;
#pragma unroll
            for (int tap = 0; tap < KH * KW; ++tap) wkA[tap] = wp[tap];
        }
        compute_store(xe, xo, wkB, obase, f0 + fi + 1, O);
    }
}

extern "C" void kernel_launch(void* const* d_in, const int* in_sizes, int n_in,
                              void* d_out, int out_size, void* d_ws, size_t ws_size,
                              hipStream_t stream) {
    const float* X  = (const float*)d_in[0];
    const float* Kw = (const float*)d_in[1];
    float* O        = (float*)d_out;
    float* Wt       = (float*)d_ws;   // 16*32*32*4 = 64 KB scratch

    transpose_weights<<<dim3(50), 256, 0, stream>>>(Kw, Wt);
    conv2d_main<<<dim3(NBLK), 256, 0, stream>>>(X, Wt, O);
}